// Round 5
// baseline (726.650 us; speedup 1.0000x reference)
//
#include <hip/hip_runtime.h>
#include <hip/hip_cooperative_groups.h>
#include <cstdint>
#include <cstddef>

#define NN 1024
#define BB 4
#define CC 256
#define HH 4
#define DD 64
#define EE 32768
#define ROWS 8
#define CAP 128
#define GRID 1024
#define NTHR 256

struct Params {
    const float *x, *ef;
    const int *src, *trg;
    const float *Wn1, *We1, *as1, *at1, *ae1;
    const float *Wn2, *We2, *as2, *at2, *ae2;
    float *out;
    float *WnT1, *WnT2, *wsum, *pe, *hbuf, *alphas, *alphat, *x1;
    int *cnt, *bucket;
};

// ---------------- device bodies ----------------

// node projection: rows r0..r0+7 of (x @ Wn.T); x rows via wave-uniform scalar loads
__device__ __forceinline__ void proj_body(const float* __restrict__ x,
                                          const float* __restrict__ WT,
                                          const float* __restrict__ a_s,
                                          const float* __restrict__ a_t,
                                          float* __restrict__ hout,
                                          float* __restrict__ alpha_s,
                                          float* __restrict__ alpha_t,
                                          int bid, int t) {
    int r0 = bid * ROWS;
    const float* xr = x + (size_t)r0 * CC;
    float acc[ROWS];
#pragma unroll
    for (int j = 0; j < ROWS; ++j) acc[j] = 0.f;
#pragma unroll 4
    for (int c = 0; c < CC; ++c) {
        float w = WT[c * CC + t];
#pragma unroll
        for (int j = 0; j < ROWS; ++j) acc[j] += w * xr[(size_t)j * CC + c];
    }
    int h = t >> 6, d = t & 63;
    float as = a_s[h * DD + d], at = a_t[h * DD + d];
#pragma unroll
    for (int j = 0; j < ROWS; ++j) {
        hout[(size_t)(r0 + j) * CC + t] = acc[j];
        float vs = acc[j] * as, vt = acc[j] * at;
#pragma unroll
        for (int off = 32; off; off >>= 1) {
            vs += __shfl_down(vs, off, 64);
            vt += __shfl_down(vt, off, 64);
        }
        if (d == 0) {
            alpha_s[(size_t)(r0 + j) * HH + h] = vs;
            alpha_t[(size_t)(r0 + j) * HH + h] = vt;
        }
    }
}

// load wsum (2 layers x 4 heads x 256) into LDS
__device__ __forceinline__ void wl_load(float* smem, const float* __restrict__ wsum, int t) {
    for (int i = t; i < 2 * HH * CC; i += NTHR) smem[i] = wsum[i];
    __syncthreads();
}

// one edge per wave: pe[l,e,h] = dot(ef[src,trg,:], wsum[l,h,:])
__device__ __forceinline__ void pe_edge(const float* smem, const Params& p, int e, int lane) {
    int s = p.src[e], g = p.trg[e];
    const float* row = p.ef + ((long)s * NN + g) * CC;
    float4 v = *(const float4*)(row + lane * 4);
    float acc[8];
#pragma unroll
    for (int i = 0; i < 8; ++i) {
        const float* w = smem + i * CC + lane * 4;
        acc[i] = v.x * w[0] + v.y * w[1] + v.z * w[2] + v.w * w[3];
    }
#pragma unroll
    for (int off = 32; off; off >>= 1)
#pragma unroll
        for (int i = 0; i < 8; ++i) acc[i] += __shfl_down(acc[i], off, 64);
    if (lane == 0) {
#pragma unroll
        for (int i = 0; i < 8; ++i) {
            int l = i >> 2, h = i & 3;
            p.pe[(size_t)l * EE * HH + (size_t)e * HH + h] = acc[i];
        }
    }
}

// block = node n; sort bucket once, aggregate all 4 batches
__device__ __forceinline__ void agg_body(const Params& p, float* smem, int n, int t,
                                         const float* __restrict__ hb,
                                         const float* __restrict__ als,
                                         const float* __restrict__ alt,
                                         const float* __restrict__ pe_l,
                                         float* __restrict__ outp) {
    float* sacc = smem;                    // 4*256
    float* sden = smem + 1024;             // 16
    int* sedge  = (int*)(smem + 1040);     // CAP
    int* ssrc   = (int*)(smem + 1040 + CAP);
    int w = t >> 6, lane = t & 63;
    int deg = p.cnt[n];
    if (deg > CAP) deg = CAP;
    if (w == 0) {
        if (deg <= 64) {
            int v = (lane < deg) ? p.bucket[n * CAP + lane] : 0x7fffffff;
            int rank = 0;
#pragma unroll
            for (int j = 0; j < 64; ++j) {
                int vj = __shfl(v, j, 64);
                rank += (vj < v) ? 1 : 0;
            }
            if (lane < deg) sedge[rank] = v;
        } else if (lane == 0) {
            for (int i = 0; i < deg; ++i) sedge[i] = p.bucket[n * CAP + i];
            for (int i = 1; i < deg; ++i) {
                int v = sedge[i], j = i - 1;
                while (j >= 0 && sedge[j] > v) { sedge[j + 1] = sedge[j]; --j; }
                sedge[j + 1] = v;
            }
        }
    }
    __syncthreads();
    if (t < deg) ssrc[t] = p.src[sedge[t]];
    __syncthreads();
    int h = lane >> 4;
    for (int b = 0; b < BB; ++b) {
        float at_n = alt[((size_t)n * BB + b) * HH + h];
        float ax = 0.f, ay = 0.f, az = 0.f, aw = 0.f, den = 0.f;
        for (int i = w; i < deg; i += 4) {
            int e = sedge[i], s = ssrc[i];
            float sc = als[((size_t)s * BB + b) * HH + h] + at_n + pe_l[(size_t)e * HH + h];
            sc = sc > 0.f ? sc : 0.2f * sc;
            float ex = __expf(sc);
            float4 v = *(const float4*)(hb + ((size_t)s * BB + b) * CC + lane * 4);
            ax += ex * v.x; ay += ex * v.y; az += ex * v.z; aw += ex * v.w;
            den += ex;
        }
        ((float4*)(sacc + w * CC))[lane] = make_float4(ax, ay, az, aw);
        if ((lane & 15) == 0) sden[w * 4 + h] = den;
        __syncthreads();
        float tot = sacc[t] + sacc[256 + t] + sacc[512 + t] + sacc[768 + t];
        int th = t >> 6;
        float dsum = sden[th] + sden[4 + th] + sden[8 + th] + sden[12 + th];
        outp[((size_t)n * BB + b) * CC + t] = tot / (dsum + 1e-16f);
        __syncthreads();
    }
}

// ---------------- cooperative fused kernel ----------------
__global__ __launch_bounds__(NTHR, 4) void k_fused(Params p) {
    cooperative_groups::grid_group grid = cooperative_groups::this_grid();
    __shared__ float smem[2080];
    int bid = blockIdx.x, t = threadIdx.x;
    int gid = bid * NTHR + t;
    int wid = t >> 6, lane = t & 63;

    // ---- P0: cnt zero + transposes + wsum ----
    if (gid < NN) p.cnt[gid] = 0;
    if (gid < CC * CC) {
        int r = gid >> 8, c = gid & 255;
        p.WnT1[gid] = p.Wn1[c * CC + r];
        p.WnT2[gid] = p.Wn2[c * CC + r];
    } else if (gid < CC * CC + 2048) {
        int idx = gid - CC * CC;
        int l = idx >> 10, h = (idx >> 8) & 3, c = idx & 255;
        const float* We = l ? p.We2 : p.We1;
        const float* ae = l ? p.ae2 : p.ae1;
        float s = 0.f;
        for (int d = 0; d < DD; ++d) s += We[(h * DD + d) * CC + c];
        p.wsum[(l * HH + h) * CC + c] = s * ae[h];
    }
    grid.sync();

    // ---- P1: proj1 (blocks 0..511) || fill + pe edges [0,12288) (blocks 512..1023) ----
    if (bid < 512) {
        proj_body(p.x, p.WnT1, p.as1, p.at1, p.hbuf, p.alphas, p.alphat, bid, t);
    } else {
        int e = (bid - 512) * NTHR + t;  // 131072 slots cover EE
        if (e < EE) {
            int n = p.trg[e];
            int pos = atomicAdd(&p.cnt[n], 1);
            if (pos < CAP) p.bucket[n * CAP + pos] = e;
        }
        wl_load(smem, p.wsum, t);
        int base = (bid - 512) * 24;  // 512 blocks * 24 = 12288 edges
#pragma unroll
        for (int k = 0; k < 6; ++k) pe_edge(smem, p, base + k * 4 + wid, lane);
    }
    grid.sync();

    // ---- P2: pe edges [12288, 32768): 20 per block ----
    if (bid < 512) wl_load(smem, p.wsum, t);  // others already have wl
    {
        int base = 12288 + bid * 20;
#pragma unroll
        for (int k = 0; k < 5; ++k) pe_edge(smem, p, base + k * 4 + wid, lane);
    }
    grid.sync();

    // ---- P3: agg layer 1 (block = node) ----
    agg_body(p, smem, bid, t, p.hbuf, p.alphas, p.alphat, p.pe, p.x1);
    grid.sync();

    // ---- P4: proj2 ----
    if (bid < 512)
        proj_body(p.x1, p.WnT2, p.as2, p.at2, p.hbuf, p.alphas, p.alphat, bid, t);
    grid.sync();

    // ---- P5: agg layer 2 ----
    agg_body(p, smem, bid, t, p.hbuf, p.alphas, p.alphat, p.pe + (size_t)EE * HH, p.out);
}

// ---------------- fallback (regular launches) ----------------
__global__ void k_fb_prep(Params p) {
    int gid = blockIdx.x * NTHR + threadIdx.x;  // 264 blocks
    if (gid < NN) p.cnt[gid] = 0;
    if (gid < CC * CC) {
        int r = gid >> 8, c = gid & 255;
        p.WnT1[gid] = p.Wn1[c * CC + r];
        p.WnT2[gid] = p.Wn2[c * CC + r];
    } else if (gid < CC * CC + 2048) {
        int idx = gid - CC * CC;
        int l = idx >> 10, h = (idx >> 8) & 3, c = idx & 255;
        const float* We = l ? p.We2 : p.We1;
        const float* ae = l ? p.ae2 : p.ae1;
        float s = 0.f;
        for (int d = 0; d < DD; ++d) s += We[(h * DD + d) * CC + c];
        p.wsum[(l * HH + h) * CC + c] = s * ae[h];
    }
}
__global__ void k_fb_fill(Params p) {
    int e = blockIdx.x * NTHR + threadIdx.x;
    if (e < EE) {
        int n = p.trg[e];
        int pos = atomicAdd(&p.cnt[n], 1);
        if (pos < CAP) p.bucket[n * CAP + pos] = e;
    }
}
__global__ void k_fb_projpe(Params p) {
    __shared__ float smem[2048];
    int bid = blockIdx.x, t = threadIdx.x;
    if (bid < 512) {
        proj_body(p.x, p.WnT1, p.as1, p.at1, p.hbuf, p.alphas, p.alphat, bid, t);
    } else {
        wl_load(smem, p.wsum, t);
        pe_edge(smem, p, (bid - 512) * 4 + (t >> 6), t & 63);
    }
}
__global__ void k_fb_agg1(Params p) {
    __shared__ float smem[2080];
    agg_body(p, smem, blockIdx.x, threadIdx.x, p.hbuf, p.alphas, p.alphat, p.pe, p.x1);
}
__global__ void k_fb_proj2(Params p) {
    proj_body(p.x1, p.WnT2, p.as2, p.at2, p.hbuf, p.alphas, p.alphat, blockIdx.x, threadIdx.x);
}
__global__ void k_fb_agg2(Params p) {
    __shared__ float smem[2080];
    agg_body(p, smem, blockIdx.x, threadIdx.x, p.hbuf, p.alphas, p.alphat,
             p.pe + (size_t)EE * HH, p.out);
}

// ---------------- launch ----------------
extern "C" void kernel_launch(void* const* d_in, const int* in_sizes, int n_in,
                              void* d_out, int out_size, void* d_ws, size_t ws_size,
                              hipStream_t stream) {
    float* wsf = (float*)d_ws;
    Params p;
    p.x   = (const float*)d_in[0];
    p.ef  = (const float*)d_in[1];
    p.src = (const int*)d_in[2];
    p.trg = (const int*)d_in[3];
    p.Wn1 = (const float*)d_in[4];
    p.We1 = (const float*)d_in[5];
    p.as1 = (const float*)d_in[6];
    p.at1 = (const float*)d_in[7];
    p.ae1 = (const float*)d_in[8];
    p.Wn2 = (const float*)d_in[9];
    p.We2 = (const float*)d_in[10];
    p.as2 = (const float*)d_in[11];
    p.at2 = (const float*)d_in[12];
    p.ae2 = (const float*)d_in[13];
    p.out = (float*)d_out;
    p.WnT1   = wsf;                 // 65536
    p.WnT2   = wsf + 65536;         // 65536
    p.wsum   = wsf + 131072;        // 2048
    p.pe     = wsf + 133120;        // 262144
    p.hbuf   = wsf + 395264;        // 1048576
    p.alphas = wsf + 1443840;       // 16384
    p.alphat = wsf + 1460224;       // 16384
    p.x1     = wsf + 1476608;       // 1048576
    p.cnt    = (int*)(wsf + 2525184);        // 1024
    p.bucket = (int*)(wsf + 2525184 + 1024); // 1024*128

    void* args[] = {(void*)&p};
    hipError_t err = hipLaunchCooperativeKernel((const void*)k_fused, dim3(GRID),
                                                dim3(NTHR), args, 0, stream);
    if (err != hipSuccess) {
        // deterministic fallback: same bodies, 6 wide launches
        k_fb_prep<<<264, NTHR, 0, stream>>>(p);
        k_fb_fill<<<128, NTHR, 0, stream>>>(p);
        k_fb_projpe<<<8704, NTHR, 0, stream>>>(p);
        k_fb_agg1<<<NN, NTHR, 0, stream>>>(p);
        k_fb_proj2<<<512, NTHR, 0, stream>>>(p);
        k_fb_agg2<<<NN, NTHR, 0, stream>>>(p);
    }
}

// Round 6
// 124.050 us; speedup vs baseline: 5.8577x; 5.8577x over previous
//
#include <hip/hip_runtime.h>
#include <cstdint>
#include <cstddef>

#define NN 1024
#define BB 4
#define CC 256
#define HH 4
#define DD 64
#define EE 32768
#define ROWS 8
#define CAP 128
#define NTHR 256

struct Params {
    const float *x, *ef;
    const int *src, *trg;
    const float *Wn1, *We1, *as1, *at1, *ae1;
    const float *Wn2, *We2, *as2, *at2, *ae2;
    float *out;
    float *WnT1, *WnT2, *wsum, *pe, *hbuf, *alphas, *alphat, *x1;
    int *cnt, *bucket;
};

// ---------------- device bodies ----------------

// node projection: rows r0..r0+7 of (x @ Wn.T); x rows via wave-uniform scalar loads
__device__ __forceinline__ void proj_body(const float* __restrict__ x,
                                          const float* __restrict__ WT,
                                          const float* __restrict__ a_s,
                                          const float* __restrict__ a_t,
                                          float* __restrict__ hout,
                                          float* __restrict__ alpha_s,
                                          float* __restrict__ alpha_t,
                                          int bid, int t) {
    int r0 = bid * ROWS;
    const float* xr = x + (size_t)r0 * CC;
    float acc[ROWS];
#pragma unroll
    for (int j = 0; j < ROWS; ++j) acc[j] = 0.f;
#pragma unroll 4
    for (int c = 0; c < CC; ++c) {
        float w = WT[c * CC + t];
#pragma unroll
        for (int j = 0; j < ROWS; ++j) acc[j] += w * xr[(size_t)j * CC + c];
    }
    int h = t >> 6, d = t & 63;
    float as = a_s[h * DD + d], at = a_t[h * DD + d];
#pragma unroll
    for (int j = 0; j < ROWS; ++j) {
        hout[(size_t)(r0 + j) * CC + t] = acc[j];
        float vs = acc[j] * as, vt = acc[j] * at;
#pragma unroll
        for (int off = 32; off; off >>= 1) {
            vs += __shfl_down(vs, off, 64);
            vt += __shfl_down(vt, off, 64);
        }
        if (d == 0) {
            alpha_s[(size_t)(r0 + j) * HH + h] = vs;
            alpha_t[(size_t)(r0 + j) * HH + h] = vt;
        }
    }
}

// one edge per wave: pe[l,e,h] = dot(ef[src,trg,:], wsum[l,h,:])
__device__ __forceinline__ void pe_edge(const float* smem, const Params& p, int e, int lane) {
    int s = p.src[e], g = p.trg[e];
    const float* row = p.ef + ((long)s * NN + g) * CC;
    float4 v = *(const float4*)(row + lane * 4);
    float acc[8];
#pragma unroll
    for (int i = 0; i < 8; ++i) {
        const float* w = smem + i * CC + lane * 4;
        acc[i] = v.x * w[0] + v.y * w[1] + v.z * w[2] + v.w * w[3];
    }
#pragma unroll
    for (int off = 32; off; off >>= 1)
#pragma unroll
        for (int i = 0; i < 8; ++i) acc[i] += __shfl_down(acc[i], off, 64);
    if (lane == 0) {
#pragma unroll
        for (int i = 0; i < 8; ++i) {
            int l = i >> 2, h = i & 3;
            p.pe[(size_t)l * EE * HH + (size_t)e * HH + h] = acc[i];
        }
    }
}

// ---------------- K1: zero cnt + transposes + wsum ----------------
__global__ __launch_bounds__(NTHR) void k_prep(Params p) {
    int gid = blockIdx.x * NTHR + threadIdx.x;  // 264 blocks
    if (gid < NN) p.cnt[gid] = 0;
    if (gid < CC * CC) {
        int r = gid >> 8, c = gid & 255;
        p.WnT1[gid] = p.Wn1[c * CC + r];
        p.WnT2[gid] = p.Wn2[c * CC + r];
    } else if (gid < CC * CC + 2048) {
        int idx = gid - CC * CC;
        int l = idx >> 10, h = (idx >> 8) & 3, c = idx & 255;
        const float* We = l ? p.We2 : p.We1;
        const float* ae = l ? p.ae2 : p.ae1;
        float s = 0.f;
        for (int d = 0; d < DD; ++d) s += We[(h * DD + d) * CC + c];
        p.wsum[(l * HH + h) * CC + c] = s * ae[h];
    }
}

// ---------------- K2: proj1 || pe || bucket-fill ----------------
// bid 0..511: proj1 ; bid 512..8703: pe (4 edges/block) ; bid 8704..8831: fill
__global__ __launch_bounds__(NTHR) void k_main1(Params p) {
    __shared__ float smem[2048];
    int bid = blockIdx.x, t = threadIdx.x;
    if (bid < 512) {
        proj_body(p.x, p.WnT1, p.as1, p.at1, p.hbuf, p.alphas, p.alphat, bid, t);
    } else if (bid < 8704) {
        for (int i = t; i < 2 * HH * CC; i += NTHR) smem[i] = p.wsum[i];
        __syncthreads();
        pe_edge(smem, p, (bid - 512) * 4 + (t >> 6), t & 63);
    } else {
        int e = (bid - 8704) * NTHR + t;
        if (e < EE) {
            int n = p.trg[e];
            int pos = atomicAdd(&p.cnt[n], 1);
            if (pos < CAP) p.bucket[n * CAP + pos] = e;
        }
    }
}

// ---------------- aggregation: block = (n,b); in-LDS deterministic sort ----------------
__global__ __launch_bounds__(NTHR) void k_agg(Params p, int layer) {
    __shared__ float sacc[4 * CC];
    __shared__ float sden[16];
    __shared__ int sedge[CAP];
    __shared__ int ssrc[CAP];
    __shared__ float spe[CAP * HH];
    const float* pe_l = p.pe + (size_t)layer * EE * HH;
    const float* als = p.alphas;
    const float* alt = p.alphat;
    const float* hb = p.hbuf;
    float* outp = layer ? p.out : p.x1;

    int t = threadIdx.x, w = t >> 6, lane = t & 63;
    int n = blockIdx.x >> 2, b = blockIdx.x & 3;
    int deg = p.cnt[n];
    if (deg > CAP) deg = CAP;
    if (w == 0) {
        if (deg <= 64) {
            int v = (lane < deg) ? p.bucket[n * CAP + lane] : 0x7fffffff;
            int rank = 0;
#pragma unroll
            for (int j = 0; j < 64; ++j) {
                int vj = __shfl(v, j, 64);
                rank += (vj < v) ? 1 : 0;
            }
            if (lane < deg) sedge[rank] = v;
        } else if (lane == 0) {
            for (int i = 0; i < deg; ++i) sedge[i] = p.bucket[n * CAP + i];
            for (int i = 1; i < deg; ++i) {
                int v = sedge[i], j = i - 1;
                while (j >= 0 && sedge[j] > v) { sedge[j + 1] = sedge[j]; --j; }
                sedge[j + 1] = v;
            }
        }
    }
    __syncthreads();
    if (t < deg) {
        int e = sedge[t];
        ssrc[t] = p.src[e];
        *(float4*)&spe[t * 4] = *(const float4*)(pe_l + (size_t)e * HH);
    }
    __syncthreads();

    int h = lane >> 4;
    float at_n = alt[((size_t)n * BB + b) * HH + h];
    float ax = 0.f, ay = 0.f, az = 0.f, aw = 0.f, den = 0.f;
#pragma unroll 2
    for (int i = w; i < deg; i += 4) {
        int s = ssrc[i];
        float sc = als[((size_t)s * BB + b) * HH + h] + at_n + spe[i * 4 + h];
        sc = sc > 0.f ? sc : 0.2f * sc;
        float ex = __expf(sc);
        float4 v = *(const float4*)(hb + ((size_t)s * BB + b) * CC + lane * 4);
        ax += ex * v.x; ay += ex * v.y; az += ex * v.z; aw += ex * v.w;
        den += ex;
    }
    ((float4*)(sacc + w * CC))[lane] = make_float4(ax, ay, az, aw);
    if ((lane & 15) == 0) sden[w * 4 + h] = den;
    __syncthreads();
    float tot = sacc[t] + sacc[256 + t] + sacc[512 + t] + sacc[768 + t];
    int th = t >> 6;
    float dsum = sden[th] + sden[4 + th] + sden[8 + th] + sden[12 + th];
    outp[((size_t)n * BB + b) * CC + t] = tot / (dsum + 1e-16f);
}

// ---------------- proj layer 2 ----------------
__global__ __launch_bounds__(NTHR) void k_proj2(Params p) {
    proj_body(p.x1, p.WnT2, p.as2, p.at2, p.hbuf, p.alphas, p.alphat,
              blockIdx.x, threadIdx.x);
}

// ---------------- launch ----------------
extern "C" void kernel_launch(void* const* d_in, const int* in_sizes, int n_in,
                              void* d_out, int out_size, void* d_ws, size_t ws_size,
                              hipStream_t stream) {
    float* wsf = (float*)d_ws;
    Params p;
    p.x   = (const float*)d_in[0];
    p.ef  = (const float*)d_in[1];
    p.src = (const int*)d_in[2];
    p.trg = (const int*)d_in[3];
    p.Wn1 = (const float*)d_in[4];
    p.We1 = (const float*)d_in[5];
    p.as1 = (const float*)d_in[6];
    p.at1 = (const float*)d_in[7];
    p.ae1 = (const float*)d_in[8];
    p.Wn2 = (const float*)d_in[9];
    p.We2 = (const float*)d_in[10];
    p.as2 = (const float*)d_in[11];
    p.at2 = (const float*)d_in[12];
    p.ae2 = (const float*)d_in[13];
    p.out = (float*)d_out;
    p.WnT1   = wsf;                 // 65536
    p.WnT2   = wsf + 65536;         // 65536
    p.wsum   = wsf + 131072;        // 2048
    p.pe     = wsf + 133120;        // 262144
    p.hbuf   = wsf + 395264;        // 1048576
    p.alphas = wsf + 1443840;       // 16384
    p.alphat = wsf + 1460224;       // 16384
    p.x1     = wsf + 1476608;       // 1048576
    p.cnt    = (int*)(wsf + 2525184);        // 1024
    p.bucket = (int*)(wsf + 2525184 + 1024); // 1024*128

    k_prep<<<264, NTHR, 0, stream>>>(p);
    k_main1<<<8832, NTHR, 0, stream>>>(p);
    k_agg<<<NN * BB, NTHR, 0, stream>>>(p, 0);
    k_proj2<<<512, NTHR, 0, stream>>>(p);
    k_agg<<<NN * BB, NTHR, 0, stream>>>(p, 1);
}

// Round 7
// 121.235 us; speedup vs baseline: 5.9938x; 1.0232x over previous
//
#include <hip/hip_runtime.h>
#include <cstdint>
#include <cstddef>

#define NN 1024
#define BB 4
#define CC 256
#define HH 4
#define DD 64
#define EE 32768
#define ROWS 8
#define CAP 128
#define NTHR 256

struct Params {
    const float *x, *ef;
    const int *src, *trg;
    const float *Wn1, *We1, *as1, *at1, *ae1;
    const float *Wn2, *We2, *as2, *at2, *ae2;
    float *out;
    float *WnT1, *WnT2, *wsum, *pe, *hbuf, *alphas, *alphat, *x1;
    int *cnt, *bucket;
};

// ---------------- proj: rows r0..r0+7 of (x @ Wn.T); x via wave-uniform scalar loads ----------------
__device__ __forceinline__ void proj_body(const float* __restrict__ x,
                                          const float* __restrict__ WT,
                                          const float* __restrict__ a_s,
                                          const float* __restrict__ a_t,
                                          float* __restrict__ hout,
                                          float* __restrict__ alpha_s,
                                          float* __restrict__ alpha_t,
                                          int bid, int t) {
    int r0 = bid * ROWS;
    const float* xr = x + (size_t)r0 * CC;
    float acc[ROWS];
#pragma unroll
    for (int j = 0; j < ROWS; ++j) acc[j] = 0.f;
#pragma unroll 4
    for (int c = 0; c < CC; ++c) {
        float w = WT[c * CC + t];
#pragma unroll
        for (int j = 0; j < ROWS; ++j) acc[j] += w * xr[(size_t)j * CC + c];
    }
    int h = t >> 6, d = t & 63;
    float as = a_s[h * DD + d], at = a_t[h * DD + d];
#pragma unroll
    for (int j = 0; j < ROWS; ++j) {
        hout[(size_t)(r0 + j) * CC + t] = acc[j];
        float vs = acc[j] * as, vt = acc[j] * at;
#pragma unroll
        for (int off = 32; off; off >>= 1) {
            vs += __shfl_down(vs, off, 64);
            vt += __shfl_down(vt, off, 64);
        }
        if (d == 0) {
            alpha_s[(size_t)(r0 + j) * HH + h] = vs;
            alpha_t[(size_t)(r0 + j) * HH + h] = vt;
        }
    }
}

// ---------------- K1: coalesced transposes + wsum + cnt zero (44 blocks) ----------------
// bid 0..31: transpose tiles (16 per matrix); 32..39: wsum; 40..43: cnt zero
__global__ __launch_bounds__(NTHR) void k_prep(Params p) {
    __shared__ float tile[64][65];
    int bid = blockIdx.x, t = threadIdx.x;
    if (bid < 32) {
        int m = bid >> 4, tl = bid & 15, ti = tl >> 2, tj = tl & 3;
        const float* W = m ? p.Wn2 : p.Wn1;
        float* WT = m ? p.WnT2 : p.WnT1;
#pragma unroll
        for (int k = 0; k < 16; ++k) {
            int idx = k * 256 + t, r = idx >> 6, c = idx & 63;
            tile[r][c] = W[(ti * 64 + r) * CC + tj * 64 + c];
        }
        __syncthreads();
#pragma unroll
        for (int k = 0; k < 16; ++k) {
            int idx = k * 256 + t, r = idx >> 6, c = idx & 63;
            WT[(tj * 64 + r) * CC + ti * 64 + c] = tile[c][r];
        }
    } else if (bid < 40) {
        int idx = (bid - 32) * 256 + t;  // [0,2048)
        int l = idx >> 10, h = (idx >> 8) & 3, c = idx & 255;
        const float* We = l ? p.We2 : p.We1;
        const float* ae = l ? p.ae2 : p.ae1;
        float s = 0.f;
        for (int d = 0; d < DD; ++d) s += We[(h * DD + d) * CC + c];
        p.wsum[(l * HH + h) * CC + c] = s * ae[h];
    } else {
        int gid = (bid - 40) * 256 + t;
        if (gid < NN) p.cnt[gid] = 0;
    }
}

// ---------------- K2: fill (first!) || proj1 || pe ----------------
// bid 0..127: bucket fill ; 128..639: proj1 ; 640..2687: pe (16 edges/block, 4/wave)
__global__ __launch_bounds__(NTHR) void k_main1(Params p) {
    int bid = blockIdx.x, t = threadIdx.x;
    if (bid < 128) {
        int e = bid * NTHR + t;
        int n = p.trg[e];
        int pos = atomicAdd(&p.cnt[n], 1);
        if (pos < CAP) p.bucket[n * CAP + pos] = e;
    } else if (bid < 640) {
        proj_body(p.x, p.WnT1, p.as1, p.at1, p.hbuf, p.alphas, p.alphat, bid - 128, t);
    } else {
        int pb = bid - 640, wid = t >> 6, lane = t & 63;
        float4 wv[8];
#pragma unroll
        for (int i = 0; i < 8; ++i)
            wv[i] = *(const float4*)(p.wsum + i * CC + lane * 4);
#pragma unroll
        for (int k = 0; k < 4; ++k) {
            int e = pb * 16 + wid * 4 + k;
            int s = p.src[e], g = p.trg[e];
            float4 v = *(const float4*)(p.ef + ((long)s * NN + g) * CC + lane * 4);
            float acc[8];
#pragma unroll
            for (int i = 0; i < 8; ++i)
                acc[i] = v.x * wv[i].x + v.y * wv[i].y + v.z * wv[i].z + v.w * wv[i].w;
#pragma unroll
            for (int off = 32; off; off >>= 1)
#pragma unroll
                for (int i = 0; i < 8; ++i) acc[i] += __shfl_down(acc[i], off, 64);
            if (lane == 0) {
                *(float4*)(p.pe + (size_t)e * HH) =
                    make_float4(acc[0], acc[1], acc[2], acc[3]);
                *(float4*)(p.pe + (size_t)EE * HH + (size_t)e * HH) =
                    make_float4(acc[4], acc[5], acc[6], acc[7]);
            }
        }
    }
}

// ---------------- agg: block = node, wave = batch; sort+stage once ----------------
__global__ __launch_bounds__(NTHR) void k_agg(Params p, int layer) {
    __shared__ int sedge[CAP];
    __shared__ int ssrc[CAP];
    __shared__ float spe[CAP * HH];
    const float* pe_l = p.pe + (size_t)layer * EE * HH;
    float* outp = layer ? p.out : p.x1;
    int t = threadIdx.x, b = t >> 6, lane = t & 63;
    int n = blockIdx.x;
    int deg = p.cnt[n];
    if (deg > CAP) deg = CAP;
    if (b == 0) {
        if (deg <= 64) {
            int v = (lane < deg) ? p.bucket[n * CAP + lane] : 0x7fffffff;
            int rank = 0;
#pragma unroll
            for (int j = 0; j < 64; ++j) {
                int vj = __shfl(v, j, 64);
                rank += (vj < v) ? 1 : 0;
            }
            if (lane < deg) sedge[rank] = v;
        } else if (lane == 0) {
            for (int i = 0; i < deg; ++i) sedge[i] = p.bucket[n * CAP + i];
            for (int i = 1; i < deg; ++i) {
                int v = sedge[i], j = i - 1;
                while (j >= 0 && sedge[j] > v) { sedge[j + 1] = sedge[j]; --j; }
                sedge[j + 1] = v;
            }
        }
    }
    __syncthreads();
    if (t < deg) {
        int e = sedge[t];
        ssrc[t] = p.src[e];
        *(float4*)&spe[t * 4] = *(const float4*)(pe_l + (size_t)e * HH);
    }
    __syncthreads();

    int h = lane >> 4;
    float at_n = p.alphat[((size_t)n * BB + b) * HH + h];
    float ax = 0.f, ay = 0.f, az = 0.f, aw = 0.f, den = 0.f;
#pragma unroll 4
    for (int i = 0; i < deg; ++i) {
        int s = ssrc[i];
        float sc = p.alphas[((size_t)s * BB + b) * HH + h] + at_n + spe[i * 4 + h];
        sc = sc > 0.f ? sc : 0.2f * sc;
        float ex = __expf(sc);
        float4 v = *(const float4*)(p.hbuf + ((size_t)s * BB + b) * CC + lane * 4);
        ax += ex * v.x; ay += ex * v.y; az += ex * v.z; aw += ex * v.w;
        den += ex;
    }
    float inv = 1.f / (den + 1e-16f);
    *(float4*)(outp + ((size_t)n * BB + b) * CC + lane * 4) =
        make_float4(ax * inv, ay * inv, az * inv, aw * inv);
}

// ---------------- proj layer 2 ----------------
__global__ __launch_bounds__(NTHR) void k_proj2(Params p) {
    proj_body(p.x1, p.WnT2, p.as2, p.at2, p.hbuf, p.alphas, p.alphat,
              blockIdx.x, threadIdx.x);
}

// ---------------- launch ----------------
extern "C" void kernel_launch(void* const* d_in, const int* in_sizes, int n_in,
                              void* d_out, int out_size, void* d_ws, size_t ws_size,
                              hipStream_t stream) {
    float* wsf = (float*)d_ws;
    Params p;
    p.x   = (const float*)d_in[0];
    p.ef  = (const float*)d_in[1];
    p.src = (const int*)d_in[2];
    p.trg = (const int*)d_in[3];
    p.Wn1 = (const float*)d_in[4];
    p.We1 = (const float*)d_in[5];
    p.as1 = (const float*)d_in[6];
    p.at1 = (const float*)d_in[7];
    p.ae1 = (const float*)d_in[8];
    p.Wn2 = (const float*)d_in[9];
    p.We2 = (const float*)d_in[10];
    p.as2 = (const float*)d_in[11];
    p.at2 = (const float*)d_in[12];
    p.ae2 = (const float*)d_in[13];
    p.out = (float*)d_out;
    p.WnT1   = wsf;                 // 65536
    p.WnT2   = wsf + 65536;         // 65536
    p.wsum   = wsf + 131072;        // 2048
    p.pe     = wsf + 133120;        // 262144
    p.hbuf   = wsf + 395264;        // 1048576
    p.alphas = wsf + 1443840;       // 16384
    p.alphat = wsf + 1460224;       // 16384
    p.x1     = wsf + 1476608;       // 1048576
    p.cnt    = (int*)(wsf + 2525184);        // 1024
    p.bucket = (int*)(wsf + 2525184 + 1024); // 1024*128

    k_prep<<<44, NTHR, 0, stream>>>(p);
    k_main1<<<2688, NTHR, 0, stream>>>(p);
    k_agg<<<NN, NTHR, 0, stream>>>(p, 0);
    k_proj2<<<512, NTHR, 0, stream>>>(p);
    k_agg<<<NN, NTHR, 0, stream>>>(p, 1);
}